// Round 12
// baseline (139.681 us; speedup 1.0000x reference)
//
#include <hip/hip_runtime.h>
#include <cstdint>

// Problem constants
constexpr int kN   = 4;
constexpr int kC   = 256;
constexpr int kS   = 2304;   // 48*48
constexpr int kDK  = 256;
constexpr int kDV  = 256;
constexpr int kDH  = 32;     // head dim
constexpr int kO   = 768;    // 2*DK + DV

typedef __bf16    bf16x8 __attribute__((ext_vector_type(8)));
typedef float     f32x4  __attribute__((ext_vector_type(4)));
typedef _Float16  f16;
typedef _Float16  f16x4  __attribute__((ext_vector_type(4)));
typedef _Float16  f16x8  __attribute__((ext_vector_type(8)));

union U4  { uint4 u; bf16x8 v; unsigned short s[8]; };
union F4  { float4 f; float a[4]; };
union UF8 { uint4 u; f16x8 v; f16 h[8]; };
union UF4 { uint2 u; f16x4 v; ushort4 su; };

#if __has_builtin(__builtin_amdgcn_exp2f)
#define EXP2(x) __builtin_amdgcn_exp2f(x)
#else
#define EXP2(x) exp2f(x)
#endif

__device__ inline float bf2f(unsigned short h) {
    unsigned int u = ((unsigned int)h) << 16;
    return __builtin_bit_cast(float, u);
}
__device__ inline unsigned short f2bf(float f) {
    unsigned int u = __builtin_bit_cast(unsigned int, f);
    u += 0x7fff + ((u >> 16) & 1);   // RNE
    return (unsigned short)(u >> 16);
}
__device__ inline void split2(float v, unsigned short& h, unsigned short& l) {
    h = f2bf(v);
    l = f2bf(v - bf2f(h));
}
__device__ inline unsigned int pk2(float a, float b) {
    auto p = __builtin_amdgcn_cvt_pkrtz(a, b);
    return __builtin_bit_cast(unsigned int, p);
}

// Fragment layouts (16x16x32 MFMA, correctness-verified rounds 6-11):
//   A/B-frag elem (row, k): lane = ((k>>3)&3)*16 + (row&15), j = k&7
//   stored [tile_row][ktile][lane 64][8]; each fragment = 512 elems contiguous.
//   C-layout: D[row = (lane>>4)*4 + reg][col = lane&15].

// ---------------------------------------------------------------------------
// prep_w (r10/r11-verified): w_qkv -> split-bf16 B-frag wh/wl
// [otile 48][kt 8][lane][8]; w_proj -> f16 A-frag wp. Grid 128.
// ---------------------------------------------------------------------------
__global__ __launch_bounds__(256) void prep_w(const float* __restrict__ w_qkv,
                                              const float* __restrict__ w_proj,
                                              unsigned short* __restrict__ wh,
                                              unsigned short* __restrict__ wl,
                                              f16* __restrict__ wp) {
    int idx = blockIdx.x * 256 + threadIdx.x;
    if (idx < 24576) {           // w_qkv: 768 o x 32 c-groups
        int o = idx >> 5, cg = idx & 31;
        F4 a0, a1;
        a0.f = *(const float4*)(w_qkv + (size_t)o * kC + cg * 8);
        a1.f = *(const float4*)(w_qkv + (size_t)o * kC + cg * 8 + 4);
        U4 hv, lv;
#pragma unroll
        for (int j = 0; j < 4; j++) split2(a0.a[j], hv.s[j], lv.s[j]);
#pragma unroll
        for (int j = 0; j < 4; j++) split2(a1.a[j], hv.s[j + 4], lv.s[j + 4]);
        size_t frag = ((size_t)(o >> 4) * 8 + (cg >> 2)) * 512 + ((cg & 3) * 16 + (o & 15)) * 8;
        *(uint4*)(wh + frag) = hv.u;
        *(uint4*)(wl + frag) = lv.u;
    } else {                     // w_proj: 256 o x 32 dv-groups
        int i2 = idx - 24576;
        int o = i2 >> 5, cg = i2 & 31;
        F4 a0, a1;
        a0.f = *(const float4*)(w_proj + (size_t)o * kDV + cg * 8);
        a1.f = *(const float4*)(w_proj + (size_t)o * kDV + cg * 8 + 4);
        UF8 w;
#pragma unroll
        for (int j = 0; j < 4; j++) w.h[j] = (f16)a0.a[j];
#pragma unroll
        for (int j = 0; j < 4; j++) w.h[j + 4] = (f16)a1.a[j];
        size_t frag = ((size_t)(o >> 4) * 8 + (cg >> 2)) * 512 + ((cg & 3) * 16 + (o & 15)) * 8;
        *(uint4*)(wp + frag) = w.u;
    }
}

// ---------------------------------------------------------------------------
// gemm_qkv (fused prep_x, r11-verified staging + NEW ping-pong B prefetch +
// more TLP): grid (36 sb, 6 y, 4 n); y = oh*2 + ohalf; block = 64 s x 128 o;
// wave = 64s x 32o (4x2 frags, split-bf16 3 MFMAs/cell). Each block stages
// its x strip [64 s][256 c] -> split-bf16 A-frag LDS (one barrier), then an
// LDS-resident K-loop with distance-1 B-frag prefetch (named ping-pong sets,
// no rotation copies). 864 blocks = 3456 waves = 3.4 waves/SIMD.
// ---------------------------------------------------------------------------
#define QKV_STEP(BH, BL, NBH, NBL, kt)                                        \
    {                                                                         \
        if ((kt) < 7) {                                                       \
            _Pragma("unroll")                                                 \
            for (int nt = 0; nt < 2; nt++) {                                  \
                U4 u;                                                         \
                u.u = *(const uint4*)(bhb + (size_t)(nt * 8 + (kt) + 1) * 512); \
                NBH[nt] = u.v;                                                \
                u.u = *(const uint4*)(blb + (size_t)(nt * 8 + (kt) + 1) * 512); \
                NBL[nt] = u.v;                                                \
            }                                                                 \
        }                                                                     \
        bf16x8 Ah[4], Al[4];                                                  \
        _Pragma("unroll")                                                     \
        for (int mt = 0; mt < 4; mt++) {                                      \
            U4 u;                                                             \
            u.u = *(const uint4*)(&AH[(kt) * 2048 + mt * 512 + lane * 8]);    \
            Ah[mt] = u.v;                                                     \
            u.u = *(const uint4*)(&AL[(kt) * 2048 + mt * 512 + lane * 8]);    \
            Al[mt] = u.v;                                                     \
        }                                                                     \
        _Pragma("unroll")                                                     \
        for (int mt = 0; mt < 4; mt++)                                        \
            _Pragma("unroll")                                                 \
            for (int nt = 0; nt < 2; nt++) {                                  \
                acc[mt][nt] = __builtin_amdgcn_mfma_f32_16x16x32_bf16(Ah[mt], BH[nt], acc[mt][nt], 0, 0, 0); \
                acc[mt][nt] = __builtin_amdgcn_mfma_f32_16x16x32_bf16(Ah[mt], BL[nt], acc[mt][nt], 0, 0, 0); \
                acc[mt][nt] = __builtin_amdgcn_mfma_f32_16x16x32_bf16(Al[mt], BH[nt], acc[mt][nt], 0, 0, 0); \
            }                                                                 \
    }

__global__ __launch_bounds__(256) void gemm_qkv(const float* __restrict__ x,
                                                const unsigned short* __restrict__ wh,
                                                const unsigned short* __restrict__ wl,
                                                const float* __restrict__ bias,
                                                f16* __restrict__ Qf,
                                                f16* __restrict__ Kf,
                                                f16* __restrict__ Vp) {
    int sb = blockIdx.x;
    int oh = blockIdx.y >> 1, ohalf = blockIdx.y & 1;
    int n  = blockIdx.z;
    int tid  = threadIdx.x;
    int wid  = tid >> 6;
    int lane = tid & 63;
    int l15  = lane & 15;
    int quad = lane >> 4;
    int s0   = sb * 64;

    __shared__ unsigned short AH[16384];   // [kt 8][mt 4][lane 64][8]
    __shared__ unsigned short AL[16384];

    // ---- stage x strip -> split-bf16 A-frag LDS (r11-verified) ----
    {
        int cg = tid >> 6, sl = tid & 63;
        const float* xb = x + (size_t)n * kC * kS + s0 + sl;
#pragma unroll
        for (int r = 0; r < 8; r++) {
            U4 hv, lv;
#pragma unroll
            for (int j = 0; j < 8; j++) {
                float v = xb[(size_t)(r * 32 + cg * 8 + j) * kS];
                split2(v, hv.s[j], lv.s[j]);
            }
            int off = r * 2048 + (sl >> 4) * 512 + (cg * 16 + (sl & 15)) * 8;
            *(uint4*)(&AH[off]) = hv.u;
            *(uint4*)(&AL[off]) = lv.u;
        }
    }
    __syncthreads();

    // otile base: o = oh*256 + ohalf*128 + wid*32 -> otile = oh*16 + ohalf*8 + wid*2
    const unsigned short* bhb = wh + ((size_t)(oh * 16 + ohalf * 8 + wid * 2) * 8) * 512
                                + (size_t)lane * 8;
    const unsigned short* blb = wl + ((size_t)(oh * 16 + ohalf * 8 + wid * 2) * 8) * 512
                                + (size_t)lane * 8;

    bf16x8 BhX[2], BlX[2], BhY[2], BlY[2];
#pragma unroll
    for (int nt = 0; nt < 2; nt++) {
        U4 u;
        u.u = *(const uint4*)(bhb + (size_t)(nt * 8) * 512); BhX[nt] = u.v;
        u.u = *(const uint4*)(blb + (size_t)(nt * 8) * 512); BlX[nt] = u.v;
    }

    f32x4 acc[4][2] = {};
    QKV_STEP(BhX, BlX, BhY, BlY, 0)
    QKV_STEP(BhY, BlY, BhX, BlX, 1)
    QKV_STEP(BhX, BlX, BhY, BlY, 2)
    QKV_STEP(BhY, BlY, BhX, BlX, 3)
    QKV_STEP(BhX, BlX, BhY, BlY, 4)
    QKV_STEP(BhY, BlY, BhX, BlX, 5)
    QKV_STEP(BhX, BlX, BhY, BlY, 6)
    QKV_STEP(BhY, BlY, BhX, BlX, 7)

    // Epilogue (r7-verified): D[row=s][col=o], row = quad*4+r, col = l15.
    constexpr float kQScale = 0.0625f * 1.4426950408889634f;
#pragma unroll
    for (int nt = 0; nt < 2; nt++) {
        int col = oh * 256 + ohalf * 128 + wid * 32 + nt * 16 + l15;
        float bcol = bias[col];
        int h   = (col >> 5) & 7;
        int d   = col & 31;
        int nh  = n * 8 + h;
#pragma unroll
        for (int mt = 0; mt < 4; mt++) {
            int row0 = s0 + mt * 16 + quad * 4;
            if (oh == 2) {
                UF4 w;
#pragma unroll
                for (int r = 0; r < 4; r++) w.v[r] = (f16)(acc[mt][nt][r] + bcol);
                int dt = (col >> 4) & 1;
                size_t off = ((((size_t)nh * 144 + (row0 >> 4)) * 2 + dt) * 64 + lane) * 4;
                *(ushort4*)(Vp + off) = w.su;
            } else if (oh == 0) {
#pragma unroll
                for (int r = 0; r < 4; r++)
                    Kf[((size_t)nh * kS + row0 + r) * kDH + d] = (f16)(acc[mt][nt][r] + bcol);
            } else {
#pragma unroll
                for (int r = 0; r < 4; r++)
                    Qf[((size_t)nh * kS + row0 + r) * kDH + d] =
                        (f16)((acc[mt][nt][r] + bcol) * kQScale);
            }
        }
    }
}

// ---------------------------------------------------------------------------
// attn v6 (r11-verified, UNCHANGED): split-t, 3 waves/block, ping-pong x2,
// max-free softmax additive partials, one combine barrier, XCD head pinning.
// Grid (8 h, 72 qw, 4 n) x 192 thr.
// ---------------------------------------------------------------------------
#define EXPPACK(tt)                                                         \
    {                                                                       \
        _Pragma("unroll")                                                   \
        for (int sqf = 0; sqf < 2; sqf++) {                                 \
            float e0 = EXP2(z[sqf][tt][0]), e1 = EXP2(z[sqf][tt][1]);       \
            float e2 = EXP2(z[sqf][tt][2]), e3 = EXP2(z[sqf][tt][3]);       \
            lsum[sqf] += (e0 + e1) + (e2 + e3);                             \
            UF4 w; w.u.x = pk2(e0, e1); w.u.y = pk2(e2, e3);                \
            pf[sqf][tt] = w.v;                                              \
        }                                                                   \
    }

#define PVSTEP(VC, tt)                                                     \
    {                                                                      \
        _Pragma("unroll")                                                  \
        for (int dt = 0; dt < 2; dt++)                                     \
            _Pragma("unroll")                                              \
            for (int sqf = 0; sqf < 2; sqf++)                              \
                oacc[dt][sqf] = __builtin_amdgcn_mfma_f32_16x16x16f16(     \
                    VC[tt][dt], pf[sqf][tt], oacc[dt][sqf], 0, 0, 0);      \
    }

#define ATTN_BODY(KC, VC, KN, VN)                                          \
    {                                                                      \
        _Pragma("unroll")                                                  \
        for (int tt = 0; tt < 4; tt++) {                                   \
            UF8 u; u.u = *(const uint4*)(kp + 2048 + tt * 512);            \
            KN[tt] = u.v;                                                  \
        }                                                                  \
        _Pragma("unroll")                                                  \
        for (int kk = 0; kk < 4; kk++) {                                   \
            UF4 u;                                                         \
            u.u = *(const uint2*)(vp + 2048 + kk * 512);       VN[kk][0] = u.v; \
            u.u = *(const uint2*)(vp + 2048 + kk * 512 + 256); VN[kk][1] = u.v; \
        }                                                                  \
        f32x4 z[2][4];                                                     \
        _Pragma("unroll")                                                  \
        for (int sqf = 0; sqf < 2; sqf++)                                  \
            _Pragma("unroll")                                              \
            for (int tt = 0; tt < 4; tt++) {                               \
                f32x4 c = {};                                              \
                z[sqf][tt] = __builtin_amdgcn_mfma_f32_16x16x32_f16(       \
                    KC[tt], qf[sqf], c, 0, 0, 0);                          \
            }                                                              \
        f16x4 pf[2][4];                                                    \
        EXPPACK(0) PVSTEP(VC, 0) EXPPACK(1) PVSTEP(VC, 1)                  \
        EXPPACK(2) PVSTEP(VC, 2) EXPPACK(3) PVSTEP(VC, 3)                  \
        kp += 2048;                                                        \
        vp += 2048;                                                        \
    }

__global__ __launch_bounds__(192) void attn_f16(const f16* __restrict__ Qf,
                                                const f16* __restrict__ Kf,
                                                const f16* __restrict__ Vp,
                                                f16* __restrict__ attnF) {
    int h = blockIdx.x, qw = blockIdx.y, n = blockIdx.z;
    int nh = n * 8 + h;
    int tid  = threadIdx.x;
    int wid  = tid >> 6;           // t-chunk 0..2
    int lane = tid & 63;
    int l15  = lane & 15;
    int quad = lane >> 4;
    int sqb  = qw * 32;

    __shared__ float Ored[2][2][2][64][4];   // [src wave-1][dt][sqf][lane][r]
    __shared__ float Lred[2][2][16];         // [src wave-1][sqf][l15]

    const f16* Qb = Qf + (size_t)nh * kS * kDH;
    const f16* kp = Kf + (size_t)nh * kS * kDH + (size_t)wid * 12 * 2048
                    + l15 * kDH + quad * 8;
    const f16* vp = Vp + (size_t)nh * 144 * 512 + (size_t)wid * 12 * 2048 + lane * 4;

    f16x8 qf[2];
    {
        UF8 u;
        u.u = *(const uint4*)(Qb + (size_t)(sqb + l15) * kDH + quad * 8);      qf[0] = u.v;
        u.u = *(const uint4*)(Qb + (size_t)(sqb + 16 + l15) * kDH + quad * 8); qf[1] = u.v;
    }

    f32x4 oacc[2][2] = {};     // [dt][sqf]: O^T[d=dt*16+quad*4+r][sq=sqf*16+l15]
    float lsum[2] = {0.f, 0.f};

    f16x8 kA[4], kB[4];
    f16x4 vA[4][2], vB[4][2];
#pragma unroll
    for (int tt = 0; tt < 4; tt++) {
        UF8 u; u.u = *(const uint4*)(kp + tt * 512); kA[tt] = u.v;
    }
#pragma unroll
    for (int kk = 0; kk < 4; kk++) {
        UF4 u;
        u.u = *(const uint2*)(vp + kk * 512);       vA[kk][0] = u.v;
        u.u = *(const uint2*)(vp + kk * 512 + 256); vA[kk][1] = u.v;
    }

    for (int it = 0; it < 6; it++) {
        ATTN_BODY(kA, vA, kB, vB)
        ATTN_BODY(kB, vB, kA, vA)
    }

#pragma unroll
    for (int sqf = 0; sqf < 2; sqf++) {
        float v = lsum[sqf];
        v += __shfl_xor(v, 16);
        v += __shfl_xor(v, 32);
        lsum[sqf] = v;
    }

    if (wid > 0) {
#pragma unroll
        for (int dt = 0; dt < 2; dt++)
#pragma unroll
            for (int sqf = 0; sqf < 2; sqf++)
                *(f32x4*)(&Ored[wid - 1][dt][sqf][lane][0]) = oacc[dt][sqf];
        if (quad == 0) {
            Lred[wid - 1][0][l15] = lsum[0];
            Lred[wid - 1][1][l15] = lsum[1];
        }
    }
    __syncthreads();
    if (wid != 0) return;

#pragma unroll
    for (int dt = 0; dt < 2; dt++)
#pragma unroll
        for (int sqf = 0; sqf < 2; sqf++) {
            oacc[dt][sqf] += *(const f32x4*)(&Ored[0][dt][sqf][lane][0]);
            oacc[dt][sqf] += *(const f32x4*)(&Ored[1][dt][sqf][lane][0]);
        }
    lsum[0] += Lred[0][0][l15] + Lred[1][0][l15];
    lsum[1] += Lred[0][1][l15] + Lred[1][1][l15];

#pragma unroll
    for (int sqf = 0; sqf < 2; sqf++) {
        float inv = 1.0f / lsum[sqf];
        int stile = qw * 2 + sqf;
#pragma unroll
        for (int dt = 0; dt < 2; dt++) {
            UF4 w;
#pragma unroll
            for (int r = 0; r < 4; r++) w.v[r] = (f16)(oacc[dt][sqf][r] * inv);
            size_t off = (((size_t)(n * 144 + stile) * 8 + h) * 512)
                         + ((dt * 2 + (quad >> 1)) * 16 + l15) * 8 + (quad & 1) * 4;
            *(uint2*)(attnF + off) = w.u;
        }
    }
}

// ---------------------------------------------------------------------------
// gemm_out v2: wave 16o x 64s (1x4 frags), grid (16, 36, 4) = 2304 waves
// (2x TLP vs r11), ping-pong prefetch (no rotation copies). LDS-free.
// ---------------------------------------------------------------------------
#define GO_STEP(AC, BC, AN, BN, kt)                                        \
    {                                                                      \
        if ((kt) < 7) {                                                    \
            UF8 u;                                                         \
            u.u = *(const uint4*)(ap + ((kt) + 1) * 512); AN = u.v;        \
            _Pragma("unroll")                                              \
            for (int i = 0; i < 4; i++) {                                  \
                u.u = *(const uint4*)(bp + (i * 8 + (kt) + 1) * 512);      \
                BN[i] = u.v;                                               \
            }                                                              \
        }                                                                  \
        _Pragma("unroll")                                                  \
        for (int nt = 0; nt < 4; nt++)                                     \
            acc[nt] = __builtin_amdgcn_mfma_f32_16x16x32_f16(AC, BC[nt],   \
                                                             acc[nt], 0, 0, 0); \
    }

__global__ __launch_bounds__(64) void gemm_out(const f16* __restrict__ wp,
                                               const f16* __restrict__ attnF,
                                               const float* __restrict__ bias,
                                               float* __restrict__ out) {
    int ob = blockIdx.x;   // 16 o-tiles of 16
    int sb = blockIdx.y;   // 36 s-tiles of 64
    int n  = blockIdx.z;
    int lane = threadIdx.x;
    int l15  = lane & 15;
    int quad = lane >> 4;

    const f16* ap = wp + ((size_t)ob * 8) * 512 + (size_t)lane * 8;
    const f16* bp = attnF + ((size_t)(n * 144 + sb * 4) * 8) * 512 + (size_t)lane * 8;

    f16x8 aX, bX[4], aY, bY[4];
    {
        UF8 u;
        u.u = *(const uint4*)(ap); aX = u.v;
#pragma unroll
        for (int i = 0; i < 4; i++) { u.u = *(const uint4*)(bp + (i * 8) * 512); bX[i] = u.v; }
    }

    f32x4 acc[4] = {};
    GO_STEP(aX, bX, aY, bY, 0)
    GO_STEP(aY, bY, aX, bX, 1)
    GO_STEP(aX, bX, aY, bY, 2)
    GO_STEP(aY, bY, aX, bX, 3)
    GO_STEP(aX, bX, aY, bY, 4)
    GO_STEP(aY, bY, aX, bX, 5)
    GO_STEP(aX, bX, aY, bY, 6)
    GO_STEP(aY, bY, aX, bX, 7)

    int row0 = ob * 16 + quad * 4;               // o
#pragma unroll
    for (int nt = 0; nt < 4; nt++) {
        int col = sb * 64 + nt * 16 + l15;       // s
#pragma unroll
        for (int r = 0; r < 4; r++)
            out[((size_t)n * kDV + row0 + r) * kS + col] = acc[nt][r] + bias[row0 + r];
    }
}

// ---------------------------------------------------------------------------
extern "C" void kernel_launch(void* const* d_in, const int* in_sizes, int n_in,
                              void* d_out, int out_size, void* d_ws, size_t ws_size,
                              hipStream_t stream) {
    const float* x      = (const float*)d_in[0];
    const float* w_qkv  = (const float*)d_in[1];
    const float* b_qkv  = (const float*)d_in[2];
    const float* w_proj = (const float*)d_in[3];
    const float* b_proj = (const float*)d_in[4];
    float* out = (float*)d_out;

    constexpr size_t kXE = (size_t)kN * kS * kC;     // 2,359,296
    unsigned short* wh = (unsigned short*)d_ws;      // w_qkv B-frag hi
    unsigned short* wl = wh + 196608;
    f16* wpF   = (f16*)(wl + 196608);                // w_proj A-frag f16
    f16* Qf    = wpF + 65536;                        // [32 nh][2304][32]
    f16* Kf    = Qf + kXE;
    f16* Vp    = Kf + kXE;                           // [32 nh][144][2][64][4]
    f16* attnF = Vp + kXE;                           // B-frag [n][144][8][512]

    prep_w<<<dim3(128), 256, 0, stream>>>(w_qkv, w_proj, wh, wl, wpF);

    gemm_qkv<<<dim3(36, 6, 4), 256, 0, stream>>>(x, wh, wl, b_qkv, Qf, Kf, Vp);

    attn_f16<<<dim3(8, 72, 4), 192, 0, stream>>>(Qf, Kf, Vp, attnF);

    gemm_out<<<dim3(16, 36, 4), 64, 0, stream>>>(wpF, attnF, b_proj, out);
}